// Round 5
// baseline (940.449 us; speedup 1.0000x reference)
//
#include <hip/hip_runtime.h>
#include <math.h>

// B=8, N=4096, D=1024, E=512, C=4096.  M = 32768.
// Split-fp16 MFMA emulation of fp32 GEMM (a = h + l/2048, 3 MFMAs) for proj;
// hi-only fp16 pass for sim + deterministic margin rescue:
//   worst-case |sim_h - sim| <= 2^-10*||p||*||c|| + eps  < 0.03 = MARGIN
//   rows with top1-top2 < MARGIN recomputed with the exact 3-MFMA path.
// R5: k_sim_h is barrier-free — A/B fragments loaded directly from global
//     (frag = contiguous 16B/lane for 16x16x32), register double-buffered.
//
// ws (MB): cn_h 0-4, cn_l 4-8, rpT_h 8-9, rpT_l 9-10, proj_h 10-42,
//          proj_l 42-74, pv1 74-78, pi1 78-82, pv2 82-86, rpv 86-90,
//          rpi 90-94, list 94-94.125, cnt @94.125

typedef _Float16 half8 __attribute__((ext_vector_type(8)));
typedef _Float16 half4 __attribute__((ext_vector_type(4)));
typedef float f32x4 __attribute__((ext_vector_type(4)));

#define INV2048 (4.8828125e-4f)
#define MARGIN 0.03f

struct Split { _Float16 h, l; };

__device__ __forceinline__ Split split_f32(float v) {
    Split s;
    s.h = (_Float16)v;
    s.l = (_Float16)((v - (float)s.h) * 2048.0f);
    return s;
}

__device__ __forceinline__ void gl_lds16(const void* g, void* l) {
    __builtin_amdgcn_global_load_lds(
        (const __attribute__((address_space(1))) unsigned int*)g,
        (__attribute__((address_space(3))) unsigned int*)l, 16, 0, 0);
}

// rp [1024,512] fp32 -> rpT_hi/lo [512,1024] f16; also zero-inits cnt
__global__ __launch_bounds__(256) void k_prep_rpt(const float* __restrict__ rp,
                                                  _Float16* __restrict__ th,
                                                  _Float16* __restrict__ tl,
                                                  int* __restrict__ cnt) {
    if (blockIdx.x == 0 && blockIdx.y == 0 && threadIdx.x == 0) *cnt = 0;
    __shared__ float tile[64][65];
    const int k0 = blockIdx.x * 64, n0 = blockIdx.y * 64;
    const int t = threadIdx.x;
    const int rr = t >> 6, cc = t & 63;
    #pragma unroll
    for (int i = 0; i < 16; ++i) {
        int r = i * 4 + rr;
        tile[r][cc] = rp[(size_t)(k0 + r) * 512 + n0 + cc];
    }
    __syncthreads();
    #pragma unroll
    for (int i = 0; i < 16; ++i) {
        int n = i * 4 + rr;
        Split s = split_f32(tile[cc][n]);
        size_t o = (size_t)(n0 + n) * 1024 + k0 + cc;
        th[o] = s.h;
        tl[o] = s.l;
    }
}

// codebook [4096,512] fp32 -> cn_hi/lo [4096,512] f16 (normalize + split)
__global__ __launch_bounds__(256) void k_norm_cb(const float* __restrict__ cb,
                                                 _Float16* __restrict__ ch,
                                                 _Float16* __restrict__ cl) {
    const int c = blockIdx.x;
    const int t = threadIdx.x;
    const float* row = cb + (size_t)c * 512;
    float v0 = row[t];
    float v1 = row[t + 256];
    float ss = v0 * v0 + v1 * v1;
    #pragma unroll
    for (int o = 32; o > 0; o >>= 1) ss += __shfl_down(ss, o, 64);
    __shared__ float wsum[4];
    if ((t & 63) == 0) wsum[t >> 6] = ss;
    __syncthreads();
    float s = 1.0f / fmaxf(sqrtf(wsum[0] + wsum[1] + wsum[2] + wsum[3]), 1e-12f);
    Split s0 = split_f32(v0 * s);
    ch[(size_t)c * 512 + t] = s0.h;
    cl[(size_t)c * 512 + t] = s0.l;
    Split s1 = split_f32(v1 * s);
    ch[(size_t)c * 512 + t + 256] = s1.h;
    cl[(size_t)c * 512 + t + 256] = s1.l;
}

// proj = x @ rp : M=32768, N=512, K=1024. split-fp16 3-MFMA (accurate).
__global__ __launch_bounds__(256, 2) void k_gemm1(const float* __restrict__ X,
                                                  const _Float16* __restrict__ Bh,
                                                  const _Float16* __restrict__ Bl,
                                                  _Float16* __restrict__ Ph,
                                                  _Float16* __restrict__ Pl) {
    __shared__ _Float16 sAh[128 * 32], sAl[128 * 32], sBh[128 * 32], sBl[128 * 32];
    const int t = threadIdx.x;
    const int nb = blockIdx.x;   // 0..3
    const int mb = blockIdx.y;   // 0..255
    const int lane = t & 63, w = t >> 6;
    const int quad = lane >> 4, l15 = lane & 15;
    const int wm = w >> 1, wn = w & 1;

    f32x4 acc[4][4], acc2[4][4];
    const f32x4 z = {0.f, 0.f, 0.f, 0.f};
    #pragma unroll
    for (int i = 0; i < 4; ++i)
        #pragma unroll
        for (int j = 0; j < 4; ++j) { acc[i][j] = z; acc2[i][j] = z; }

    const int srow = w * 32 + (lane >> 2);
    const int kcol = (lane & 3) * 8;
    const _Float16* gBh = Bh + (size_t)(nb * 128 + srow) * 1024 + kcol;
    const _Float16* gBl = Bl + (size_t)(nb * 128 + srow) * 1024 + kcol;
    const float* Xb = X + (size_t)(mb * 128) * 1024;

    for (int ks = 0; ks < 32; ++ks) {
        const int ko = ks * 32;
        __syncthreads();
        gl_lds16(gBh + ko, &sBh[w * 1024]);
        gl_lds16(gBh + ko + (size_t)16 * 1024, &sBh[w * 1024 + 512]);
        gl_lds16(gBl + ko, &sBl[w * 1024]);
        gl_lds16(gBl + ko + (size_t)16 * 1024, &sBl[w * 1024 + 512]);
        #pragma unroll
        for (int i = 0; i < 4; ++i) {
            int c = i * 256 + t;
            int row = c >> 3, kq = (c & 7) * 4;
            float4 v = *(const float4*)(Xb + (size_t)row * 1024 + ko + kq);
            Split sx = split_f32(v.x), sy = split_f32(v.y);
            Split sz = split_f32(v.z), sw = split_f32(v.w);
            half4 hv, lv;
            hv.x = sx.h; hv.y = sy.h; hv.z = sz.h; hv.w = sw.h;
            lv.x = sx.l; lv.y = sy.l; lv.z = sz.l; lv.w = sw.l;
            *(half4*)&sAh[row * 32 + kq] = hv;
            *(half4*)&sAl[row * 32 + kq] = lv;
        }
        __syncthreads();
        half8 ah[4], al[4], bh[4], bl[4];
        #pragma unroll
        for (int i = 0; i < 4; ++i) {
            ah[i] = *(const half8*)&sAh[(wm * 64 + i * 16 + l15) * 32 + quad * 8];
            al[i] = *(const half8*)&sAl[(wm * 64 + i * 16 + l15) * 32 + quad * 8];
            bh[i] = *(const half8*)&sBh[(wn * 64 + i * 16 + l15) * 32 + quad * 8];
            bl[i] = *(const half8*)&sBl[(wn * 64 + i * 16 + l15) * 32 + quad * 8];
        }
        #pragma unroll
        for (int mi = 0; mi < 4; ++mi)
            #pragma unroll
            for (int ni = 0; ni < 4; ++ni) {
                acc[mi][ni]  = __builtin_amdgcn_mfma_f32_16x16x32_f16(ah[mi], bh[ni], acc[mi][ni], 0, 0, 0);
                acc2[mi][ni] = __builtin_amdgcn_mfma_f32_16x16x32_f16(ah[mi], bl[ni], acc2[mi][ni], 0, 0, 0);
                acc2[mi][ni] = __builtin_amdgcn_mfma_f32_16x16x32_f16(al[mi], bh[ni], acc2[mi][ni], 0, 0, 0);
            }
    }
    #pragma unroll
    for (int mi = 0; mi < 4; ++mi)
        #pragma unroll
        for (int r = 0; r < 4; ++r) {
            int row = mb * 128 + wm * 64 + mi * 16 + quad * 4 + r;
            #pragma unroll
            for (int ni = 0; ni < 4; ++ni) {
                int col = nb * 128 + wn * 64 + ni * 16 + l15;
                float v = acc[mi][ni][r] + acc2[mi][ni][r] * INV2048;
                Split s = split_f32(v);
                Ph[(size_t)row * 512 + col] = s.h;
                Pl[(size_t)row * 512 + col] = s.l;
            }
        }
}

// PASS 1: hi-only sim, barrier-free. A/B frags direct from global
// (16x16x32 A-frag = A[m=l15][k=quad*8+j] -> contiguous 16B per lane),
// register double-buffered; LDS used only for the tiny epilogue combine.
__global__ __launch_bounds__(256, 3) void k_sim_h(const _Float16* __restrict__ Ah,
                                                  const _Float16* __restrict__ Bh,
                                                  float* __restrict__ pv1,
                                                  int* __restrict__ pi1,
                                                  float* __restrict__ pv2) {
    __shared__ float v1s[128][2], v2s[128][2];
    __shared__ int   i1s[128][2];
    const int t = threadIdx.x;
    const int cbk = blockIdx.x;  // 0..31
    const int mb = blockIdx.y;   // 0..255
    const int lane = t & 63, w = t >> 6;
    const int quad = lane >> 4, l15 = lane & 15;
    const int wm = w >> 1, wn = w & 1;

    f32x4 acc[4][4];
    const f32x4 z = {0.f, 0.f, 0.f, 0.f};
    #pragma unroll
    for (int i = 0; i < 4; ++i)
        #pragma unroll
        for (int j = 0; j < 4; ++j) acc[i][j] = z;

    // per-lane frag base: row = m0 + l15 (+ mi*16), byte col = k*2
    const _Float16* aB = Ah + (size_t)(mb * 128 + wm * 64 + l15) * 512 + quad * 8;
    const _Float16* bB = Bh + (size_t)(cbk * 128 + wn * 64 + l15) * 512 + quad * 8;

    half8 a0[4], b0[4], a1[4], b1[4];
    #pragma unroll
    for (int i = 0; i < 4; ++i) {
        a0[i] = *(const half8*)(aB + (size_t)i * 16 * 512);
        b0[i] = *(const half8*)(bB + (size_t)i * 16 * 512);
    }
    for (int ks = 0; ks < 16; ks += 2) {
        // prefetch odd iter
        #pragma unroll
        for (int i = 0; i < 4; ++i) {
            a1[i] = *(const half8*)(aB + (size_t)i * 16 * 512 + (ks + 1) * 32);
            b1[i] = *(const half8*)(bB + (size_t)i * 16 * 512 + (ks + 1) * 32);
        }
        #pragma unroll
        for (int mi = 0; mi < 4; ++mi)
            #pragma unroll
            for (int ni = 0; ni < 4; ++ni)
                acc[mi][ni] = __builtin_amdgcn_mfma_f32_16x16x32_f16(a0[mi], b0[ni], acc[mi][ni], 0, 0, 0);
        // prefetch next even iter
        if (ks + 2 < 16) {
            #pragma unroll
            for (int i = 0; i < 4; ++i) {
                a0[i] = *(const half8*)(aB + (size_t)i * 16 * 512 + (ks + 2) * 32);
                b0[i] = *(const half8*)(bB + (size_t)i * 16 * 512 + (ks + 2) * 32);
            }
        }
        #pragma unroll
        for (int mi = 0; mi < 4; ++mi)
            #pragma unroll
            for (int ni = 0; ni < 4; ++ni)
                acc[mi][ni] = __builtin_amdgcn_mfma_f32_16x16x32_f16(a1[mi], b1[ni], acc[mi][ni], 0, 0, 0);
    }

    // top-2 per row: lane-local over 4 cols, then 16-lane butterfly merge
    #pragma unroll
    for (int mi = 0; mi < 4; ++mi)
        #pragma unroll
        for (int r = 0; r < 4; ++r) {
            float v1 = -INFINITY, v2 = -INFINITY;
            int i1 = 0x7fffffff;
            #pragma unroll
            for (int ni = 0; ni < 4; ++ni) {
                float v = acc[mi][ni][r];
                int col = cbk * 128 + wn * 64 + ni * 16 + l15;
                if (v > v1 || (v == v1 && col < i1)) { v2 = v1; v1 = v; i1 = col; }
                else if (v > v2) v2 = v;
            }
            #pragma unroll
            for (int o = 1; o < 16; o <<= 1) {
                float ov1 = __shfl_xor(v1, o, 64);
                int oi1 = __shfl_xor(i1, o, 64);
                float ov2 = __shfl_xor(v2, o, 64);
                if (ov1 > v1 || (ov1 == v1 && oi1 < i1)) { v2 = fmaxf(v1, ov2); v1 = ov1; i1 = oi1; }
                else v2 = fmaxf(v2, ov1);
            }
            if (l15 == 0) {
                int row = wm * 64 + mi * 16 + quad * 4 + r;
                v1s[row][wn] = v1; i1s[row][wn] = i1; v2s[row][wn] = v2;
            }
        }
    __syncthreads();
    if (t < 128) {
        float v1 = v1s[t][0], v2 = v2s[t][0];
        int i1 = i1s[t][0];
        float ov1 = v1s[t][1], ov2 = v2s[t][1];
        int oi1 = i1s[t][1];
        if (ov1 > v1 || (ov1 == v1 && oi1 < i1)) { v2 = fmaxf(v1, ov2); v1 = ov1; i1 = oi1; }
        else v2 = fmaxf(v2, ov1);
        size_t o = (size_t)(mb * 128 + t) * 32 + cbk;
        pv1[o] = v1; pi1[o] = i1; pv2[o] = v2;
    }
}

// reduce 32 c-tile partials; commit confident rows, queue contested ones
__global__ __launch_bounds__(256) void k_flag(const float* __restrict__ pv1,
                                              const int* __restrict__ pi1,
                                              const float* __restrict__ pv2,
                                              int* __restrict__ out,
                                              int* __restrict__ list,
                                              int* __restrict__ cnt) {
    int r = blockIdx.x * 256 + threadIdx.x;
    if (r >= 32768) return;
    size_t base = (size_t)r * 32;
    float v1 = pv1[base], v2 = pv2[base];
    int i1 = pi1[base];
    #pragma unroll
    for (int j = 1; j < 32; ++j) {
        float ov1 = pv1[base + j], ov2 = pv2[base + j];
        int oi1 = pi1[base + j];
        if (ov1 > v1 || (ov1 == v1 && oi1 < i1)) { v2 = fmaxf(v1, ov2); v1 = ov1; i1 = oi1; }
        else v2 = fmaxf(v2, ov1);
    }
    out[r] = i1;
    if (v1 - v2 < MARGIN) {
        int p = atomicAdd(cnt, 1);
        list[p] = r;
    }
}

// PASS 2: exact 3-MFMA sim on gathered contested rows
__global__ __launch_bounds__(256, 2) void k_sim_fix(const _Float16* __restrict__ Ah,
                                                    const _Float16* __restrict__ Al,
                                                    const _Float16* __restrict__ Bh,
                                                    const _Float16* __restrict__ Bl,
                                                    const int* __restrict__ list,
                                                    const int* __restrict__ cnt,
                                                    float* __restrict__ rpv,
                                                    int* __restrict__ rpi) {
    __shared__ _Float16 sAh[128 * 32], sAl[128 * 32], sBh[128 * 32], sBl[128 * 32];
    __shared__ int rowidx[128];
    __shared__ float pvs[128][2];
    __shared__ int   pis[128][2];
    const int count = *cnt;
    const int t = threadIdx.x;
    const int cbk = blockIdx.x;  // 0..31
    const int lane = t & 63, w = t >> 6;
    const int quad = lane >> 4, l15 = lane & 15;
    const int wm = w >> 1, wn = w & 1;

    const int srow = w * 32 + (lane >> 2);
    const int kcol = (lane & 3) * 8;
    const _Float16* gBh = Bh + (size_t)(cbk * 128 + srow) * 512 + kcol;
    const _Float16* gBl = Bl + (size_t)(cbk * 128 + srow) * 512 + kcol;

    for (int g = blockIdx.y; g * 128 < count; g += gridDim.y) {
        __syncthreads();
        if (t < 128) {
            int p = g * 128 + t;
            rowidx[t] = (p < count) ? list[p] : list[0];
        }
        __syncthreads();

        f32x4 acc[4][4], acc2[4][4];
        const f32x4 z = {0.f, 0.f, 0.f, 0.f};
        #pragma unroll
        for (int i = 0; i < 4; ++i)
            #pragma unroll
            for (int j = 0; j < 4; ++j) { acc[i][j] = z; acc2[i][j] = z; }

        for (int ks = 0; ks < 16; ++ks) {
            const int ko = ks * 32;
            __syncthreads();
            gl_lds16(gBh + ko, &sBh[w * 1024]);
            gl_lds16(gBh + ko + (size_t)16 * 512, &sBh[w * 1024 + 512]);
            gl_lds16(gBl + ko, &sBl[w * 1024]);
            gl_lds16(gBl + ko + (size_t)16 * 512, &sBl[w * 1024 + 512]);
            #pragma unroll
            for (int i = 0; i < 2; ++i) {
                int idx = i * 256 + t;          // 0..511
                int row = idx >> 2, seg = (idx & 3) * 8;
                size_t src = (size_t)rowidx[row] * 512 + ko + seg;
                *(half8*)&sAh[row * 32 + seg] = *(const half8*)(Ah + src);
                *(half8*)&sAl[row * 32 + seg] = *(const half8*)(Al + src);
            }
            __syncthreads();
            half8 ah[4], al[4], bh[4], bl[4];
            #pragma unroll
            for (int i = 0; i < 4; ++i) {
                ah[i] = *(const half8*)&sAh[(wm * 64 + i * 16 + l15) * 32 + quad * 8];
                al[i] = *(const half8*)&sAl[(wm * 64 + i * 16 + l15) * 32 + quad * 8];
                bh[i] = *(const half8*)&sBh[(wn * 64 + i * 16 + l15) * 32 + quad * 8];
                bl[i] = *(const half8*)&sBl[(wn * 64 + i * 16 + l15) * 32 + quad * 8];
            }
            #pragma unroll
            for (int mi = 0; mi < 4; ++mi)
                #pragma unroll
                for (int ni = 0; ni < 4; ++ni) {
                    acc[mi][ni]  = __builtin_amdgcn_mfma_f32_16x16x32_f16(ah[mi], bh[ni], acc[mi][ni], 0, 0, 0);
                    acc2[mi][ni] = __builtin_amdgcn_mfma_f32_16x16x32_f16(ah[mi], bl[ni], acc2[mi][ni], 0, 0, 0);
                    acc2[mi][ni] = __builtin_amdgcn_mfma_f32_16x16x32_f16(al[mi], bh[ni], acc2[mi][ni], 0, 0, 0);
                }
        }

        #pragma unroll
        for (int mi = 0; mi < 4; ++mi)
            #pragma unroll
            for (int r = 0; r < 4; ++r) {
                float bv = -INFINITY;
                int bi = 0x7fffffff;
                #pragma unroll
                for (int ni = 0; ni < 4; ++ni) {
                    float v = acc[mi][ni][r] + acc2[mi][ni][r] * INV2048;
                    int col = cbk * 128 + wn * 64 + ni * 16 + l15;
                    if (v > bv || (v == bv && col < bi)) { bv = v; bi = col; }
                }
                #pragma unroll
                for (int o = 1; o < 16; o <<= 1) {
                    float ov = __shfl_xor(bv, o, 64);
                    int oi = __shfl_xor(bi, o, 64);
                    if (ov > bv || (ov == bv && oi < bi)) { bv = ov; bi = oi; }
                }
                if (l15 == 0) {
                    int row = wm * 64 + mi * 16 + quad * 4 + r;
                    pvs[row][wn] = bv; pis[row][wn] = bi;
                }
            }
        __syncthreads();
        if (t < 128 && g * 128 + t < count) {
            float v0 = pvs[t][0], v1 = pvs[t][1];
            int i0 = pis[t][0], i1 = pis[t][1];
            bool sw = (v1 > v0) || (v1 == v0 && i1 < i0);
            size_t o = (size_t)(g * 128 + t) * 32 + cbk;
            rpv[o] = sw ? v1 : v0;
            rpi[o] = sw ? i1 : i0;
        }
    }
}

__global__ __launch_bounds__(256) void k_fix(const float* __restrict__ rpv,
                                             const int* __restrict__ rpi,
                                             const int* __restrict__ list,
                                             const int* __restrict__ cnt,
                                             int* __restrict__ out) {
    int p = blockIdx.x * 256 + threadIdx.x;
    if (p >= *cnt) return;
    size_t base = (size_t)p * 32;
    float bv = -INFINITY;
    int bi = 0x7fffffff;
    #pragma unroll
    for (int j = 0; j < 32; ++j) {
        float v = rpv[base + j];
        int ci = rpi[base + j];
        if (v > bv || (v == bv && ci < bi)) { bv = v; bi = ci; }
    }
    out[list[p]] = bi;
}

extern "C" void kernel_launch(void* const* d_in, const int* in_sizes, int n_in,
                              void* d_out, int out_size, void* d_ws, size_t ws_size,
                              hipStream_t stream) {
    const float* x  = (const float*)d_in[0];   // [8,4096,1024]
    const float* rp = (const float*)d_in[1];   // [1024,512]
    const float* cb = (const float*)d_in[2];   // [4096,512]
    int* out = (int*)d_out;                    // [32768] int32

    char* ws = (char*)d_ws;
    _Float16* cn_h   = (_Float16*)(ws);
    _Float16* cn_l   = (_Float16*)(ws + ((size_t)4 << 20));
    _Float16* rpT_h  = (_Float16*)(ws + ((size_t)8 << 20));
    _Float16* rpT_l  = (_Float16*)(ws + ((size_t)9 << 20));
    _Float16* proj_h = (_Float16*)(ws + ((size_t)10 << 20));
    _Float16* proj_l = (_Float16*)(ws + ((size_t)42 << 20));
    float*    pv1    = (float*)   (ws + ((size_t)74 << 20));
    int*      pi1    = (int*)     (ws + ((size_t)78 << 20));
    float*    pv2    = (float*)   (ws + ((size_t)82 << 20));
    float*    rpv    = (float*)   (ws + ((size_t)86 << 20));
    int*      rpi    = (int*)     (ws + ((size_t)90 << 20));
    int*      list   = (int*)     (ws + ((size_t)94 << 20));
    int*      cnt    = (int*)     (ws + ((size_t)94 << 20) + (128 << 10));

    k_prep_rpt<<<dim3(16, 8), 256, 0, stream>>>(rp, rpT_h, rpT_l, cnt);
    k_norm_cb<<<4096, 256, 0, stream>>>(cb, cn_h, cn_l);
    k_gemm1<<<dim3(4, 256), 256, 0, stream>>>(x, rpT_h, rpT_l, proj_h, proj_l);
    k_sim_h<<<dim3(32, 256), 256, 0, stream>>>(proj_h, cn_h, pv1, pi1, pv2);
    k_flag<<<128, 256, 0, stream>>>(pv1, pi1, pv2, out, list, cnt);
    k_sim_fix<<<dim3(32, 32), 256, 0, stream>>>(proj_h, proj_l, cn_h, cn_l, list, cnt, rpv, rpi);
    k_fix<<<128, 256, 0, stream>>>(rpv, rpi, list, cnt, out);
}

// Round 6
// 609.344 us; speedup vs baseline: 1.5434x; 1.5434x over previous
//
#include <hip/hip_runtime.h>
#include <math.h>

// B=8, N=4096, D=1024, E=512, C=4096.  M = 32768.
// Split-fp16 MFMA emulation of fp32 GEMM (a = h + l/2048, 3 MFMAs) for proj;
// hi-only fp16 pass for sim + deterministic margin rescue:
//   worst-case |sim_h - sim| <= 2^-10*||p||*||c|| + eps  < 0.03 = MARGIN
//   rows with top1-top2 < MARGIN recomputed with the exact 3-MFMA path.
// R6: k_sim_h = r4 LDS structure + ping-pong buffers with prefetch issued
//     AFTER the (single) barrier, + XOR k-seg swizzle to kill 4-way LDS
//     read conflicts. gl_lds dest stays contiguous (wave-uniform base).
//
// ws (MB): cn_h 0-4, cn_l 4-8, rpT_h 8-9, rpT_l 9-10, proj_h 10-42,
//          proj_l 42-74, pv1 74-78, pi1 78-82, pv2 82-86, rpv 86-90,
//          rpi 90-94, list 94-94.125, cnt @94.125

typedef _Float16 half8 __attribute__((ext_vector_type(8)));
typedef _Float16 half4 __attribute__((ext_vector_type(4)));
typedef float f32x4 __attribute__((ext_vector_type(4)));

#define INV2048 (4.8828125e-4f)
#define MARGIN 0.03f

struct Split { _Float16 h, l; };

__device__ __forceinline__ Split split_f32(float v) {
    Split s;
    s.h = (_Float16)v;
    s.l = (_Float16)((v - (float)s.h) * 2048.0f);
    return s;
}

__device__ __forceinline__ void gl_lds16(const void* g, void* l) {
    __builtin_amdgcn_global_load_lds(
        (const __attribute__((address_space(1))) unsigned int*)g,
        (__attribute__((address_space(3))) unsigned int*)l, 16, 0, 0);
}

// rp [1024,512] fp32 -> rpT_hi/lo [512,1024] f16; also zero-inits cnt
__global__ __launch_bounds__(256) void k_prep_rpt(const float* __restrict__ rp,
                                                  _Float16* __restrict__ th,
                                                  _Float16* __restrict__ tl,
                                                  int* __restrict__ cnt) {
    if (blockIdx.x == 0 && blockIdx.y == 0 && threadIdx.x == 0) *cnt = 0;
    __shared__ float tile[64][65];
    const int k0 = blockIdx.x * 64, n0 = blockIdx.y * 64;
    const int t = threadIdx.x;
    const int rr = t >> 6, cc = t & 63;
    #pragma unroll
    for (int i = 0; i < 16; ++i) {
        int r = i * 4 + rr;
        tile[r][cc] = rp[(size_t)(k0 + r) * 512 + n0 + cc];
    }
    __syncthreads();
    #pragma unroll
    for (int i = 0; i < 16; ++i) {
        int n = i * 4 + rr;
        Split s = split_f32(tile[cc][n]);
        size_t o = (size_t)(n0 + n) * 1024 + k0 + cc;
        th[o] = s.h;
        tl[o] = s.l;
    }
}

// codebook [4096,512] fp32 -> cn_hi/lo [4096,512] f16 (normalize + split)
__global__ __launch_bounds__(256) void k_norm_cb(const float* __restrict__ cb,
                                                 _Float16* __restrict__ ch,
                                                 _Float16* __restrict__ cl) {
    const int c = blockIdx.x;
    const int t = threadIdx.x;
    const float* row = cb + (size_t)c * 512;
    float v0 = row[t];
    float v1 = row[t + 256];
    float ss = v0 * v0 + v1 * v1;
    #pragma unroll
    for (int o = 32; o > 0; o >>= 1) ss += __shfl_down(ss, o, 64);
    __shared__ float wsum[4];
    if ((t & 63) == 0) wsum[t >> 6] = ss;
    __syncthreads();
    float s = 1.0f / fmaxf(sqrtf(wsum[0] + wsum[1] + wsum[2] + wsum[3]), 1e-12f);
    Split s0 = split_f32(v0 * s);
    ch[(size_t)c * 512 + t] = s0.h;
    cl[(size_t)c * 512 + t] = s0.l;
    Split s1 = split_f32(v1 * s);
    ch[(size_t)c * 512 + t + 256] = s1.h;
    cl[(size_t)c * 512 + t + 256] = s1.l;
}

// proj = x @ rp : M=32768, N=512, K=1024. split-fp16 3-MFMA (accurate).
__global__ __launch_bounds__(256, 2) void k_gemm1(const float* __restrict__ X,
                                                  const _Float16* __restrict__ Bh,
                                                  const _Float16* __restrict__ Bl,
                                                  _Float16* __restrict__ Ph,
                                                  _Float16* __restrict__ Pl) {
    __shared__ _Float16 sAh[128 * 32], sAl[128 * 32], sBh[128 * 32], sBl[128 * 32];
    const int t = threadIdx.x;
    const int nb = blockIdx.x;   // 0..3
    const int mb = blockIdx.y;   // 0..255
    const int lane = t & 63, w = t >> 6;
    const int quad = lane >> 4, l15 = lane & 15;
    const int wm = w >> 1, wn = w & 1;

    f32x4 acc[4][4], acc2[4][4];
    const f32x4 z = {0.f, 0.f, 0.f, 0.f};
    #pragma unroll
    for (int i = 0; i < 4; ++i)
        #pragma unroll
        for (int j = 0; j < 4; ++j) { acc[i][j] = z; acc2[i][j] = z; }

    const int srow = w * 32 + (lane >> 2);
    const int kcol = (lane & 3) * 8;
    const _Float16* gBh = Bh + (size_t)(nb * 128 + srow) * 1024 + kcol;
    const _Float16* gBl = Bl + (size_t)(nb * 128 + srow) * 1024 + kcol;
    const float* Xb = X + (size_t)(mb * 128) * 1024;

    for (int ks = 0; ks < 32; ++ks) {
        const int ko = ks * 32;
        __syncthreads();
        gl_lds16(gBh + ko, &sBh[w * 1024]);
        gl_lds16(gBh + ko + (size_t)16 * 1024, &sBh[w * 1024 + 512]);
        gl_lds16(gBl + ko, &sBl[w * 1024]);
        gl_lds16(gBl + ko + (size_t)16 * 1024, &sBl[w * 1024 + 512]);
        #pragma unroll
        for (int i = 0; i < 4; ++i) {
            int c = i * 256 + t;
            int row = c >> 3, kq = (c & 7) * 4;
            float4 v = *(const float4*)(Xb + (size_t)row * 1024 + ko + kq);
            Split sx = split_f32(v.x), sy = split_f32(v.y);
            Split sz = split_f32(v.z), sw = split_f32(v.w);
            half4 hv, lv;
            hv.x = sx.h; hv.y = sy.h; hv.z = sz.h; hv.w = sw.h;
            lv.x = sx.l; lv.y = sy.l; lv.z = sz.l; lv.w = sw.l;
            *(half4*)&sAh[row * 32 + kq] = hv;
            *(half4*)&sAl[row * 32 + kq] = lv;
        }
        __syncthreads();
        half8 ah[4], al[4], bh[4], bl[4];
        #pragma unroll
        for (int i = 0; i < 4; ++i) {
            ah[i] = *(const half8*)&sAh[(wm * 64 + i * 16 + l15) * 32 + quad * 8];
            al[i] = *(const half8*)&sAl[(wm * 64 + i * 16 + l15) * 32 + quad * 8];
            bh[i] = *(const half8*)&sBh[(wn * 64 + i * 16 + l15) * 32 + quad * 8];
            bl[i] = *(const half8*)&sBl[(wn * 64 + i * 16 + l15) * 32 + quad * 8];
        }
        #pragma unroll
        for (int mi = 0; mi < 4; ++mi)
            #pragma unroll
            for (int ni = 0; ni < 4; ++ni) {
                acc[mi][ni]  = __builtin_amdgcn_mfma_f32_16x16x32_f16(ah[mi], bh[ni], acc[mi][ni], 0, 0, 0);
                acc2[mi][ni] = __builtin_amdgcn_mfma_f32_16x16x32_f16(ah[mi], bl[ni], acc2[mi][ni], 0, 0, 0);
                acc2[mi][ni] = __builtin_amdgcn_mfma_f32_16x16x32_f16(al[mi], bh[ni], acc2[mi][ni], 0, 0, 0);
            }
    }
    #pragma unroll
    for (int mi = 0; mi < 4; ++mi)
        #pragma unroll
        for (int r = 0; r < 4; ++r) {
            int row = mb * 128 + wm * 64 + mi * 16 + quad * 4 + r;
            #pragma unroll
            for (int ni = 0; ni < 4; ++ni) {
                int col = nb * 128 + wn * 64 + ni * 16 + l15;
                float v = acc[mi][ni][r] + acc2[mi][ni][r] * INV2048;
                Split s = split_f32(v);
                Ph[(size_t)row * 512 + col] = s.h;
                Pl[(size_t)row * 512 + col] = s.l;
            }
        }
}

// PASS 1: hi-only sim. Ping-pong LDS; prefetch issued AFTER the barrier so
// the next barrier's vmcnt drain waits on loads that had a full iteration
// in flight. XOR k-seg swizzle: LDS(row, slot) = global(row, slot^((row>>1)&3)).
__global__ __launch_bounds__(256, 4) void k_sim_h(const _Float16* __restrict__ Ah,
                                                  const _Float16* __restrict__ Bh,
                                                  float* __restrict__ pv1,
                                                  int* __restrict__ pi1,
                                                  float* __restrict__ pv2) {
    __shared__ _Float16 sA[2][4096], sB[2][4096];
    __shared__ float v1s[128][2], v2s[128][2];
    __shared__ int   i1s[128][2];
    const int t = threadIdx.x;
    const int cbk = blockIdx.x;  // 0..31
    const int mb = blockIdx.y;   // 0..255
    const int lane = t & 63, w = t >> 6;
    const int quad = lane >> 4, l15 = lane & 15;
    const int wm = w >> 1, wn = w & 1;

    f32x4 acc[4][4];
    const f32x4 z = {0.f, 0.f, 0.f, 0.f};
    #pragma unroll
    for (int i = 0; i < 4; ++i)
        #pragma unroll
        for (int j = 0; j < 4; ++j) acc[i][j] = z;

    // staging: wave w covers tile rows [w*32, w*32+32) as 2 gl_lds chunks of
    // 16 rows; lane ell loads global (row = chunk0 + (ell>>2),
    // seg = (ell&3)^((ell>>3)&3)) so the contiguous LDS dest realizes the swizzle.
    const int srow = lane >> 2;
    const int kseg = (lane & 3) ^ ((lane >> 3) & 3);
    const _Float16* gA = Ah + (size_t)(mb * 128 + w * 32 + srow) * 512 + kseg * 8;
    const _Float16* gB = Bh + (size_t)(cbk * 128 + w * 32 + srow) * 512 + kseg * 8;

    // read swizzle: constant per lane (rows differ by multiples of 2 in the
    // varying bits that matter: ((r>>1)&3) == ((l15>>1)&3) for all frags)
    const int sw8 = (quad ^ ((l15 >> 1) & 3)) * 8;

    // prologue: fill buffer 0
    gl_lds16(gA, &sA[0][w * 1024]);
    gl_lds16(gA + (size_t)16 * 512, &sA[0][w * 1024 + 512]);
    gl_lds16(gB, &sB[0][w * 1024]);
    gl_lds16(gB + (size_t)16 * 512, &sB[0][w * 1024 + 512]);

    for (int ks = 0; ks < 16; ++ks) {
        const int p = ks & 1;
        __syncthreads();   // drains prefetch issued last iter; guards buf reuse
        if (ks + 1 < 16) {
            const int ko = (ks + 1) * 32;
            gl_lds16(gA + ko, &sA[p ^ 1][w * 1024]);
            gl_lds16(gA + ko + (size_t)16 * 512, &sA[p ^ 1][w * 1024 + 512]);
            gl_lds16(gB + ko, &sB[p ^ 1][w * 1024]);
            gl_lds16(gB + ko + (size_t)16 * 512, &sB[p ^ 1][w * 1024 + 512]);
        }
        half8 a[4], b[4];
        #pragma unroll
        for (int i = 0; i < 4; ++i) {
            a[i] = *(const half8*)&sA[p][(wm * 64 + i * 16 + l15) * 32 + sw8];
            b[i] = *(const half8*)&sB[p][(wn * 64 + i * 16 + l15) * 32 + sw8];
        }
        #pragma unroll
        for (int mi = 0; mi < 4; ++mi)
            #pragma unroll
            for (int ni = 0; ni < 4; ++ni)
                acc[mi][ni] = __builtin_amdgcn_mfma_f32_16x16x32_f16(a[mi], b[ni], acc[mi][ni], 0, 0, 0);
    }

    // top-2 per row: lane-local over 4 cols, then 16-lane butterfly merge
    #pragma unroll
    for (int mi = 0; mi < 4; ++mi)
        #pragma unroll
        for (int r = 0; r < 4; ++r) {
            float v1 = -INFINITY, v2 = -INFINITY;
            int i1 = 0x7fffffff;
            #pragma unroll
            for (int ni = 0; ni < 4; ++ni) {
                float v = acc[mi][ni][r];
                int col = cbk * 128 + wn * 64 + ni * 16 + l15;
                if (v > v1 || (v == v1 && col < i1)) { v2 = v1; v1 = v; i1 = col; }
                else if (v > v2) v2 = v;
            }
            #pragma unroll
            for (int o = 1; o < 16; o <<= 1) {
                float ov1 = __shfl_xor(v1, o, 64);
                int oi1 = __shfl_xor(i1, o, 64);
                float ov2 = __shfl_xor(v2, o, 64);
                if (ov1 > v1 || (ov1 == v1 && oi1 < i1)) { v2 = fmaxf(v1, ov2); v1 = ov1; i1 = oi1; }
                else v2 = fmaxf(v2, ov1);
            }
            if (l15 == 0) {
                int row = wm * 64 + mi * 16 + quad * 4 + r;
                v1s[row][wn] = v1; i1s[row][wn] = i1; v2s[row][wn] = v2;
            }
        }
    __syncthreads();
    if (t < 128) {
        float v1 = v1s[t][0], v2 = v2s[t][0];
        int i1 = i1s[t][0];
        float ov1 = v1s[t][1], ov2 = v2s[t][1];
        int oi1 = i1s[t][1];
        if (ov1 > v1 || (ov1 == v1 && oi1 < i1)) { v2 = fmaxf(v1, ov2); v1 = ov1; i1 = oi1; }
        else v2 = fmaxf(v2, ov1);
        size_t o = (size_t)(mb * 128 + t) * 32 + cbk;
        pv1[o] = v1; pi1[o] = i1; pv2[o] = v2;
    }
}

// reduce 32 c-tile partials; commit confident rows, queue contested ones
__global__ __launch_bounds__(256) void k_flag(const float* __restrict__ pv1,
                                              const int* __restrict__ pi1,
                                              const float* __restrict__ pv2,
                                              int* __restrict__ out,
                                              int* __restrict__ list,
                                              int* __restrict__ cnt) {
    int r = blockIdx.x * 256 + threadIdx.x;
    if (r >= 32768) return;
    size_t base = (size_t)r * 32;
    float v1 = pv1[base], v2 = pv2[base];
    int i1 = pi1[base];
    #pragma unroll
    for (int j = 1; j < 32; ++j) {
        float ov1 = pv1[base + j], ov2 = pv2[base + j];
        int oi1 = pi1[base + j];
        if (ov1 > v1 || (ov1 == v1 && oi1 < i1)) { v2 = fmaxf(v1, ov2); v1 = ov1; i1 = oi1; }
        else v2 = fmaxf(v2, ov1);
    }
    out[r] = i1;
    if (v1 - v2 < MARGIN) {
        int p = atomicAdd(cnt, 1);
        list[p] = r;
    }
}

// PASS 2: exact 3-MFMA sim on gathered contested rows
__global__ __launch_bounds__(256, 2) void k_sim_fix(const _Float16* __restrict__ Ah,
                                                    const _Float16* __restrict__ Al,
                                                    const _Float16* __restrict__ Bh,
                                                    const _Float16* __restrict__ Bl,
                                                    const int* __restrict__ list,
                                                    const int* __restrict__ cnt,
                                                    float* __restrict__ rpv,
                                                    int* __restrict__ rpi) {
    __shared__ _Float16 sAh[128 * 32], sAl[128 * 32], sBh[128 * 32], sBl[128 * 32];
    __shared__ int rowidx[128];
    __shared__ float pvs[128][2];
    __shared__ int   pis[128][2];
    const int count = *cnt;
    const int t = threadIdx.x;
    const int cbk = blockIdx.x;  // 0..31
    const int lane = t & 63, w = t >> 6;
    const int quad = lane >> 4, l15 = lane & 15;
    const int wm = w >> 1, wn = w & 1;

    const int srow = w * 32 + (lane >> 2);
    const int kcol = (lane & 3) * 8;
    const _Float16* gBh = Bh + (size_t)(cbk * 128 + srow) * 512 + kcol;
    const _Float16* gBl = Bl + (size_t)(cbk * 128 + srow) * 512 + kcol;

    for (int g = blockIdx.y; g * 128 < count; g += gridDim.y) {
        __syncthreads();
        if (t < 128) {
            int p = g * 128 + t;
            rowidx[t] = (p < count) ? list[p] : list[0];
        }
        __syncthreads();

        f32x4 acc[4][4], acc2[4][4];
        const f32x4 z = {0.f, 0.f, 0.f, 0.f};
        #pragma unroll
        for (int i = 0; i < 4; ++i)
            #pragma unroll
            for (int j = 0; j < 4; ++j) { acc[i][j] = z; acc2[i][j] = z; }

        for (int ks = 0; ks < 16; ++ks) {
            const int ko = ks * 32;
            __syncthreads();
            gl_lds16(gBh + ko, &sBh[w * 1024]);
            gl_lds16(gBh + ko + (size_t)16 * 512, &sBh[w * 1024 + 512]);
            gl_lds16(gBl + ko, &sBl[w * 1024]);
            gl_lds16(gBl + ko + (size_t)16 * 512, &sBl[w * 1024 + 512]);
            #pragma unroll
            for (int i = 0; i < 2; ++i) {
                int idx = i * 256 + t;          // 0..511
                int row = idx >> 2, seg = (idx & 3) * 8;
                size_t src = (size_t)rowidx[row] * 512 + ko + seg;
                *(half8*)&sAh[row * 32 + seg] = *(const half8*)(Ah + src);
                *(half8*)&sAl[row * 32 + seg] = *(const half8*)(Al + src);
            }
            __syncthreads();
            half8 ah[4], al[4], bh[4], bl[4];
            #pragma unroll
            for (int i = 0; i < 4; ++i) {
                ah[i] = *(const half8*)&sAh[(wm * 64 + i * 16 + l15) * 32 + quad * 8];
                al[i] = *(const half8*)&sAl[(wm * 64 + i * 16 + l15) * 32 + quad * 8];
                bh[i] = *(const half8*)&sBh[(wn * 64 + i * 16 + l15) * 32 + quad * 8];
                bl[i] = *(const half8*)&sBl[(wn * 64 + i * 16 + l15) * 32 + quad * 8];
            }
            #pragma unroll
            for (int mi = 0; mi < 4; ++mi)
                #pragma unroll
                for (int ni = 0; ni < 4; ++ni) {
                    acc[mi][ni]  = __builtin_amdgcn_mfma_f32_16x16x32_f16(ah[mi], bh[ni], acc[mi][ni], 0, 0, 0);
                    acc2[mi][ni] = __builtin_amdgcn_mfma_f32_16x16x32_f16(ah[mi], bl[ni], acc2[mi][ni], 0, 0, 0);
                    acc2[mi][ni] = __builtin_amdgcn_mfma_f32_16x16x32_f16(al[mi], bh[ni], acc2[mi][ni], 0, 0, 0);
                }
        }

        #pragma unroll
        for (int mi = 0; mi < 4; ++mi)
            #pragma unroll
            for (int r = 0; r < 4; ++r) {
                float bv = -INFINITY;
                int bi = 0x7fffffff;
                #pragma unroll
                for (int ni = 0; ni < 4; ++ni) {
                    float v = acc[mi][ni][r] + acc2[mi][ni][r] * INV2048;
                    int col = cbk * 128 + wn * 64 + ni * 16 + l15;
                    if (v > bv || (v == bv && col < bi)) { bv = v; bi = col; }
                }
                #pragma unroll
                for (int o = 1; o < 16; o <<= 1) {
                    float ov = __shfl_xor(bv, o, 64);
                    int oi = __shfl_xor(bi, o, 64);
                    if (ov > bv || (ov == bv && oi < bi)) { bv = ov; bi = oi; }
                }
                if (l15 == 0) {
                    int row = wm * 64 + mi * 16 + quad * 4 + r;
                    pvs[row][wn] = bv; pis[row][wn] = bi;
                }
            }
        __syncthreads();
        if (t < 128 && g * 128 + t < count) {
            float v0 = pvs[t][0], v1 = pvs[t][1];
            int i0 = pis[t][0], i1 = pis[t][1];
            bool sw = (v1 > v0) || (v1 == v0 && i1 < i0);
            size_t o = (size_t)(g * 128 + t) * 32 + cbk;
            rpv[o] = sw ? v1 : v0;
            rpi[o] = sw ? i1 : i0;
        }
    }
}

__global__ __launch_bounds__(256) void k_fix(const float* __restrict__ rpv,
                                             const int* __restrict__ rpi,
                                             const int* __restrict__ list,
                                             const int* __restrict__ cnt,
                                             int* __restrict__ out) {
    int p = blockIdx.x * 256 + threadIdx.x;
    if (p >= *cnt) return;
    size_t base = (size_t)p * 32;
    float bv = -INFINITY;
    int bi = 0x7fffffff;
    #pragma unroll
    for (int j = 0; j < 32; ++j) {
        float v = rpv[base + j];
        int ci = rpi[base + j];
        if (v > bv || (v == bv && ci < bi)) { bv = v; bi = ci; }
    }
    out[list[p]] = bi;
}

extern "C" void kernel_launch(void* const* d_in, const int* in_sizes, int n_in,
                              void* d_out, int out_size, void* d_ws, size_t ws_size,
                              hipStream_t stream) {
    const float* x  = (const float*)d_in[0];   // [8,4096,1024]
    const float* rp = (const float*)d_in[1];   // [1024,512]
    const float* cb = (const float*)d_in[2];   // [4096,512]
    int* out = (int*)d_out;                    // [32768] int32

    char* ws = (char*)d_ws;
    _Float16* cn_h   = (_Float16*)(ws);
    _Float16* cn_l   = (_Float16*)(ws + ((size_t)4 << 20));
    _Float16* rpT_h  = (_Float16*)(ws + ((size_t)8 << 20));
    _Float16* rpT_l  = (_Float16*)(ws + ((size_t)9 << 20));
    _Float16* proj_h = (_Float16*)(ws + ((size_t)10 << 20));
    _Float16* proj_l = (_Float16*)(ws + ((size_t)42 << 20));
    float*    pv1    = (float*)   (ws + ((size_t)74 << 20));
    int*      pi1    = (int*)     (ws + ((size_t)78 << 20));
    float*    pv2    = (float*)   (ws + ((size_t)82 << 20));
    float*    rpv    = (float*)   (ws + ((size_t)86 << 20));
    int*      rpi    = (int*)     (ws + ((size_t)90 << 20));
    int*      list   = (int*)     (ws + ((size_t)94 << 20));
    int*      cnt    = (int*)     (ws + ((size_t)94 << 20) + (128 << 10));

    k_prep_rpt<<<dim3(16, 8), 256, 0, stream>>>(rp, rpT_h, rpT_l, cnt);
    k_norm_cb<<<4096, 256, 0, stream>>>(cb, cn_h, cn_l);
    k_gemm1<<<dim3(4, 256), 256, 0, stream>>>(x, rpT_h, rpT_l, proj_h, proj_l);
    k_sim_h<<<dim3(32, 256), 256, 0, stream>>>(proj_h, cn_h, pv1, pi1, pv2);
    k_flag<<<128, 256, 0, stream>>>(pv1, pi1, pv2, out, list, cnt);
    k_sim_fix<<<dim3(32, 32), 256, 0, stream>>>(proj_h, proj_l, cn_h, cn_l, list, cnt, rpv, rpi);
    k_fix<<<128, 256, 0, stream>>>(rpv, rpi, list, cnt, out);
}